// Round 1
// baseline (11214.581 us; speedup 1.0000x reference)
//
#include <hip/hip_runtime.h>
#include <math.h>

constexpr int kB = 4;
constexpr int kL = 512;
constexpr int kH = 1024;
constexpr int kNH = 16;
constexpr int kNL = 4;
constexpr int kDK = 64;
constexpr int kDFF = 4096;
constexpr int kM = kB * kL;  // 2048
constexpr float kNEG = -1e18f;
constexpr float kInvSqrt2 = 0.70710678118654752440f;

// ---------------------------------------------------------------- sin/cos
__global__ __launch_bounds__(256) void sincos_kernel(const int* __restrict__ leaf_idx,
                                                     float* __restrict__ sinT,
                                                     float* __restrict__ cosT) {
  int idx = blockIdx.x * 256 + threadIdx.x;  // kB*kL*32
  int d = idx & 31;
  int bl = idx >> 5;
  float pos = (float)leaf_idx[bl];
  // inv_freq = 10000^(-d/32)
  float freq = expf(-(float)d * (9.210340371976184f / 32.f));
  float ang = pos * freq;
  sinT[idx] = sinf(ang);
  cosT[idx] = cosf(ang);
}

// ---------------------------------------------------------------- layernorm
__global__ __launch_bounds__(256) void ln_kernel(const float* __restrict__ x,
                                                 const float* __restrict__ g,
                                                 const float* __restrict__ b,
                                                 float* __restrict__ out) {
  int row = blockIdx.x;
  int t = threadIdx.x;
  const float4* xr = (const float4*)(x + (size_t)row * kH);
  float4 v = xr[t];
  float s = v.x + v.y + v.z + v.w;
  float ss = v.x * v.x + v.y * v.y + v.z * v.z + v.w * v.w;
#pragma unroll
  for (int o = 32; o > 0; o >>= 1) {
    s += __shfl_down(s, o);
    ss += __shfl_down(ss, o);
  }
  __shared__ float redS[4], redQ[4];
  __shared__ float muS, invS;
  int w = t >> 6;
  if ((t & 63) == 0) {
    redS[w] = s;
    redQ[w] = ss;
  }
  __syncthreads();
  if (t == 0) {
    float S = redS[0] + redS[1] + redS[2] + redS[3];
    float Q = redQ[0] + redQ[1] + redQ[2] + redQ[3];
    float mu = S * (1.f / kH);
    float var = Q * (1.f / kH) - mu * mu;
    muS = mu;
    invS = rsqrtf(var + 1e-5f);
  }
  __syncthreads();
  float mu = muS, inv = invS;
  float4 gv = ((const float4*)g)[t];
  float4 bv = ((const float4*)b)[t];
  float4 o;
  o.x = (v.x - mu) * inv * gv.x + bv.x;
  o.y = (v.y - mu) * inv * gv.y + bv.y;
  o.z = (v.z - mu) * inv * gv.z + bv.z;
  o.w = (v.w - mu) * inv * gv.w + bv.w;
  ((float4*)(out + (size_t)row * kH))[t] = o;
}

// ---------------------------------------------------------------- GEMM
// EPI: 0 plain, 1 qkv transpose-write (*scale), 2 residual add, 3 exact GELU
template <int EPI>
__global__ __launch_bounds__(256) void gemm_kernel(const float* __restrict__ A,
                                                   const float* __restrict__ W,
                                                   const float* __restrict__ bias,
                                                   float* __restrict__ C, int K, int N,
                                                   float scale) {
  __shared__ __align__(16) float As[8][132];
  __shared__ __align__(16) float Ws[8][128];
  int t = threadIdx.x;
  int bx = blockIdx.x, by = blockIdx.y;
  int tx = t & 15, ty = t >> 4;
  float acc[8][8];
#pragma unroll
  for (int i = 0; i < 8; i++)
#pragma unroll
    for (int j = 0; j < 8; j++) acc[i][j] = 0.f;

  int ar = t >> 1, ac4 = t & 1;
  int wr = t >> 5, wc4 = t & 31;
  const float* Aload = A + (size_t)(by * 128 + ar) * K + ac4 * 4;
  const float* Wload = W + (size_t)wr * N + bx * 128 + wc4 * 4;

  for (int k0 = 0; k0 < K; k0 += 8) {
    float4 a = *(const float4*)(Aload + k0);
    float4 w = *(const float4*)(Wload + (size_t)k0 * N);
    __syncthreads();
    As[ac4 * 4 + 0][ar] = a.x;
    As[ac4 * 4 + 1][ar] = a.y;
    As[ac4 * 4 + 2][ar] = a.z;
    As[ac4 * 4 + 3][ar] = a.w;
    *(float4*)&Ws[wr][wc4 * 4] = w;
    __syncthreads();
#pragma unroll
    for (int k = 0; k < 8; k++) {
      float4 a0 = *(const float4*)&As[k][ty * 8];
      float4 a1 = *(const float4*)&As[k][ty * 8 + 4];
      float4 w0 = *(const float4*)&Ws[k][tx * 8];
      float4 w1 = *(const float4*)&Ws[k][tx * 8 + 4];
      float av[8] = {a0.x, a0.y, a0.z, a0.w, a1.x, a1.y, a1.z, a1.w};
      float wv[8] = {w0.x, w0.y, w0.z, w0.w, w1.x, w1.y, w1.z, w1.w};
#pragma unroll
      for (int i = 0; i < 8; i++)
#pragma unroll
        for (int j = 0; j < 8; j++) acc[i][j] = fmaf(av[i], wv[j], acc[i][j]);
    }
  }
#pragma unroll
  for (int i = 0; i < 8; i++) {
    int m = by * 128 + ty * 8 + i;
#pragma unroll
    for (int j = 0; j < 8; j++) {
      int n = bx * 128 + tx * 8 + j;
      float val = acc[i][j] + bias[n];
      if (EPI == 0) {
        C[(size_t)m * N + n] = val;
      } else if (EPI == 1) {
        val *= scale;
        int bb = m >> 9, l = m & 511;
        int hd = n >> 6, d = n & 63;
        C[((size_t)(bb * kNH + hd) * kL + l) * kDK + d] = val;
      } else if (EPI == 2) {
        C[(size_t)m * N + n] += val;
      } else {
        val = 0.5f * val * (1.f + erff(val * kInvSqrt2));
        C[(size_t)m * N + n] = val;
      }
    }
  }
}

// ---------------------------------------------------------------- gate
__global__ __launch_bounds__(256) void gate_kernel(const float* __restrict__ h,
                                                   const float* __restrict__ Wg,
                                                   const float* __restrict__ bg,
                                                   const int* __restrict__ leaf_idx,
                                                   float* __restrict__ gate) {
  int row = blockIdx.x;
  int t = threadIdx.x;
  int o = t & 15, s = t >> 4;
  const float* hr = h + (size_t)row * kH;
  float acc = 0.f;
#pragma unroll 4
  for (int k = s * 64; k < s * 64 + 64; k++) acc = fmaf(hr[k], Wg[k * kNH + o], acc);
  __shared__ float red[16][17];
  red[s][o] = acc;
  __syncthreads();
  if (t < 16) {
    float z = bg[t];
#pragma unroll
    for (int i = 0; i < 16; i++) z += red[i][t];
    float gv = 1.f / (1.f + expf(-z));
    if (leaf_idx[row] == 0) gv = 1.f;
    int b = row >> 9, l = row & 511;
    gate[((size_t)(b * kNH + t)) * kL + l] = gv;
  }
}

// ---------------------------------------------------------------- rotary
__global__ __launch_bounds__(256) void rotary_kernel(const float* __restrict__ q,
                                                     const float* __restrict__ k,
                                                     const float* __restrict__ sinT,
                                                     const float* __restrict__ cosT,
                                                     float* __restrict__ tq,
                                                     float* __restrict__ tk) {
  int idx = blockIdx.x * 256 + threadIdx.x;  // kB*kNH*kL*32
  int d2 = idx & 31;
  int l = (idx >> 5) & (kL - 1);
  int hh = (idx >> 14) & (kNH - 1);
  int b = idx >> 18;
  size_t base = ((size_t)(b * kNH + hh) * kL + l) * kDK + d2 * 2;
  int sidx = (b * kL + l) * 32 + d2;
  float sn = sinT[sidx], cs = cosT[sidx];
  float x1 = q[base], x2 = q[base + 1];
  tq[base] = x1 * cs - x2 * sn;
  tq[base + 1] = x2 * cs + x1 * sn;
  x1 = k[base];
  x2 = k[base + 1];
  tk[base] = x1 * cs - x2 * sn;
  tk[base + 1] = x2 * cs + x1 * sn;
}

// ---------------------------------------------------------------- attention scores + softmax + blend
// block = (b, h, 16 q rows); wave w owns q rows 4w..4w+3; lane = k index within tile.
// Scores stay in registers: s[tile][r] holds score for k = tile*64 + lane.
__global__ __launch_bounds__(256) void attn_score_kernel(
    const float* __restrict__ q, const float* __restrict__ k,
    const float* __restrict__ tq, const float* __restrict__ tk,
    const float* __restrict__ tree_score, const float* __restrict__ gate,
    const int* __restrict__ leaf_idx, float* __restrict__ attn) {
  __shared__ __align__(16) float kt[64][68];
  __shared__ __align__(16) float tkt[64][68];
  __shared__ __align__(16) float qt[16][68];
  __shared__ __align__(16) float tqt[16][68];

  int t = threadIdx.x;
  int blk = blockIdx.x;  // ((b*NH+h)*32 + qtile)
  int qtile = blk & 31;
  int bh = blk >> 5;
  int b = bh >> 4;
  int q0 = qtile * 16;
  size_t headoff = (size_t)bh * kL * kDK;

  {
    int r = t >> 4, c4 = t & 15;
    *(float4*)&qt[r][c4 * 4] = *(const float4*)(q + headoff + (size_t)(q0 + r) * kDK + c4 * 4);
    *(float4*)&tqt[r][c4 * 4] = *(const float4*)(tq + headoff + (size_t)(q0 + r) * kDK + c4 * 4);
  }

  int wave = t >> 6, lane = t & 63;
  float s_t[8][4], s_l[8][4];

#pragma unroll
  for (int tile = 0; tile < 8; tile++) {
    int kt0 = tile * 64;
    __syncthreads();
    {
      int c4 = t & 15;
#pragma unroll
      for (int jj = 0; jj < 4; jj++) {
        int r = (t >> 4) + jj * 16;
        *(float4*)&kt[r][c4 * 4] = *(const float4*)(k + headoff + (size_t)(kt0 + r) * kDK + c4 * 4);
        *(float4*)&tkt[r][c4 * 4] = *(const float4*)(tk + headoff + (size_t)(kt0 + r) * kDK + c4 * 4);
      }
    }
    __syncthreads();

    float at[4] = {0.f, 0.f, 0.f, 0.f};
    float al[4] = {0.f, 0.f, 0.f, 0.f};
#pragma unroll
    for (int i4 = 0; i4 < 16; i4++) {
      float4 kv = *(const float4*)&kt[lane][i4 * 4];
      float4 tkv = *(const float4*)&tkt[lane][i4 * 4];
#pragma unroll
      for (int r = 0; r < 4; r++) {
        float4 qv = *(const float4*)&qt[wave * 4 + r][i4 * 4];
        float4 tqv = *(const float4*)&tqt[wave * 4 + r][i4 * 4];
        at[r] = fmaf(qv.x, kv.x, at[r]);
        at[r] = fmaf(qv.y, kv.y, at[r]);
        at[r] = fmaf(qv.z, kv.z, at[r]);
        at[r] = fmaf(qv.w, kv.w, at[r]);
        al[r] = fmaf(tqv.x, tkv.x, al[r]);
        al[r] = fmaf(tqv.y, tkv.y, al[r]);
        al[r] = fmaf(tqv.z, tkv.z, al[r]);
        al[r] = fmaf(tqv.w, tkv.w, al[r]);
      }
    }
    int kvld = (leaf_idx[b * kL + kt0 + lane] != 0);
#pragma unroll
    for (int r = 0; r < 4; r++) {
      int qg = q0 + wave * 4 + r;
      float ts = tree_score[((size_t)bh * kL + qg) * kL + kt0 + lane];
      s_t[tile][r] = kvld ? (at[r] + ts) * kInvSqrt2 : kNEG;
      s_l[tile][r] = kvld ? al[r] : kNEG;
    }
  }

  // softmax (tree & leaf) + gate blend, per q row, row spread across 64 lanes x 8 slots
#pragma unroll
  for (int r = 0; r < 4; r++) {
    int qg = q0 + wave * 4 + r;
    int qvld = (leaf_idx[b * kL + qg] != 0);
    float g = gate[(size_t)bh * kL + qg];
    float mt = -INFINITY, ml = -INFINITY;
#pragma unroll
    for (int j = 0; j < 8; j++) {
      float svl = qvld ? s_l[j][r] : kNEG;
      s_l[j][r] = svl;
      mt = fmaxf(mt, s_t[j][r]);
      ml = fmaxf(ml, svl);
    }
#pragma unroll
    for (int o = 32; o > 0; o >>= 1) {
      mt = fmaxf(mt, __shfl_xor(mt, o));
      ml = fmaxf(ml, __shfl_xor(ml, o));
    }
    float pt[8], pl[8];
    float sumt = 0.f, suml = 0.f;
#pragma unroll
    for (int j = 0; j < 8; j++) {
      pt[j] = expf(s_t[j][r] - mt);
      sumt += pt[j];
      pl[j] = expf(s_l[j][r] - ml);
      suml += pl[j];
    }
#pragma unroll
    for (int o = 32; o > 0; o >>= 1) {
      sumt += __shfl_xor(sumt, o);
      suml += __shfl_xor(suml, o);
    }
    float it = g / sumt, il = (1.f - g) / suml;
    float* arow = attn + ((size_t)bh * kL + qg) * kL;
#pragma unroll
    for (int j = 0; j < 8; j++) arow[j * 64 + lane] = pt[j] * it + pl[j] * il;
  }
}

// ---------------------------------------------------------------- ctx = attn @ v
__global__ __launch_bounds__(256) void attn_ctx_kernel(const float* __restrict__ attn,
                                                       const float* __restrict__ v,
                                                       float* __restrict__ ctx) {
  __shared__ __align__(16) float vt[64][68];
  __shared__ __align__(16) float at[32][68];
  int t = threadIdx.x;
  int blk = blockIdx.x;  // ((b*NH+h)*16 + q32)
  int q32 = blk & 15;
  int bh = blk >> 4;
  int q0 = q32 * 32;
  int wave = t >> 6, lane = t & 63;
  size_t headoff = (size_t)bh * kL * kDK;
  float acc[8] = {0.f, 0.f, 0.f, 0.f, 0.f, 0.f, 0.f, 0.f};
  for (int kt0 = 0; kt0 < kL; kt0 += 64) {
    __syncthreads();
    {
      int c4 = t & 15;
#pragma unroll
      for (int jj = 0; jj < 4; jj++) {
        int r = (t >> 4) + jj * 16;
        *(float4*)&vt[r][c4 * 4] = *(const float4*)(v + headoff + (size_t)(kt0 + r) * kDK + c4 * 4);
      }
#pragma unroll
      for (int jj = 0; jj < 2; jj++) {
        int idx = t + jj * 256;
        int r = idx >> 4, cc = idx & 15;
        *(float4*)&at[r][cc * 4] =
            *(const float4*)(attn + ((size_t)bh * kL + q0 + r) * kL + kt0 + cc * 4);
      }
    }
    __syncthreads();
#pragma unroll
    for (int kk = 0; kk < 64; kk += 4) {
      float v0 = vt[kk][lane], v1 = vt[kk + 1][lane], v2 = vt[kk + 2][lane], v3 = vt[kk + 3][lane];
#pragma unroll
      for (int r = 0; r < 8; r++) {
        float4 a = *(const float4*)&at[wave * 8 + r][kk];
        acc[r] = fmaf(a.x, v0, acc[r]);
        acc[r] = fmaf(a.y, v1, acc[r]);
        acc[r] = fmaf(a.z, v2, acc[r]);
        acc[r] = fmaf(a.w, v3, acc[r]);
      }
    }
  }
  int b = bh >> 4, hh = bh & 15;
#pragma unroll
  for (int r = 0; r < 8; r++) {
    int qg = q0 + wave * 8 + r;
    ctx[((size_t)b * kL + qg) * kH + hh * kDK + lane] = acc[r];
  }
}

// ---------------------------------------------------------------- launch
extern "C" void kernel_launch(void* const* d_in, const int* in_sizes, int n_in,
                              void* d_out, int out_size, void* d_ws, size_t ws_size,
                              hipStream_t stream) {
  (void)in_sizes;
  (void)n_in;
  (void)out_size;
  (void)ws_size;
  const float* content = (const float*)d_in[0];
  const float* tree_score = (const float*)d_in[1];
  const float* Wq = (const float*)d_in[2];
  const float* bq = (const float*)d_in[3];
  const float* Wk = (const float*)d_in[4];
  const float* bk = (const float*)d_in[5];
  const float* Wv = (const float*)d_in[6];
  const float* bv = (const float*)d_in[7];
  const float* Wo = (const float*)d_in[8];
  const float* bo = (const float*)d_in[9];
  const float* Wg = (const float*)d_in[10];
  const float* bg = (const float*)d_in[11];
  const float* W1 = (const float*)d_in[12];
  const float* b1 = (const float*)d_in[13];
  const float* W2 = (const float*)d_in[14];
  const float* b2 = (const float*)d_in[15];
  const float* ln1_g = (const float*)d_in[16];
  const float* ln1_b = (const float*)d_in[17];
  const float* ln2_g = (const float*)d_in[18];
  const float* ln2_b = (const float*)d_in[19];
  // d_in[20] = mask (bool) — identical to leaf_idx==0, unused
  const int* leaf_idx = (const int*)d_in[21];

  float* x = (float*)d_out;
  float* p = (float*)d_ws;
  float* sinT = p; p += kB * kL * 32;
  float* cosT = p; p += kB * kL * 32;
  float* h = p;    p += (size_t)kM * kH;
  float* qb = p;   p += (size_t)kM * kH;
  float* kb = p;   p += (size_t)kM * kH;
  float* vb = p;   p += (size_t)kM * kH;
  float* tqb = p;  p += (size_t)kM * kH;
  float* tkb = p;  p += (size_t)kM * kH;
  float* gateb = p; p += kB * kNH * kL;
  float* ctx = p;  p += (size_t)kM * kH;
  float* attn = p;  // kB*kNH*kL*kL floats
  float* ffn = attn;  // aliased: attn dead by the time FFN runs

  hipMemcpyAsync(x, content, (size_t)kM * kH * sizeof(float), hipMemcpyDeviceToDevice, stream);
  sincos_kernel<<<kB * kL * 32 / 256, 256, 0, stream>>>(leaf_idx, sinT, cosT);

  for (int i = 0; i < kNL; i++) {
    const float* Wq_i = Wq + (size_t)i * kH * kH;
    const float* Wk_i = Wk + (size_t)i * kH * kH;
    const float* Wv_i = Wv + (size_t)i * kH * kH;
    const float* Wo_i = Wo + (size_t)i * kH * kH;
    const float* Wg_i = Wg + (size_t)i * kH * kNH;
    const float* W1_i = W1 + (size_t)i * kH * kDFF;
    const float* W2_i = W2 + (size_t)i * kDFF * kH;

    ln_kernel<<<kM, 256, 0, stream>>>(x, ln1_g + i * kH, ln1_b + i * kH, h);
    gemm_kernel<1><<<dim3(kH / 128, kM / 128), 256, 0, stream>>>(h, Wq_i, bq + i * kH, qb, kH, kH, 0.125f);
    gemm_kernel<1><<<dim3(kH / 128, kM / 128), 256, 0, stream>>>(h, Wk_i, bk + i * kH, kb, kH, kH, 1.f);
    gemm_kernel<1><<<dim3(kH / 128, kM / 128), 256, 0, stream>>>(h, Wv_i, bv + i * kH, vb, kH, kH, 1.f);
    gate_kernel<<<kM, 256, 0, stream>>>(h, Wg_i, bg + i * kNH, leaf_idx, gateb);
    rotary_kernel<<<kB * kNH * kL * 32 / 256, 256, 0, stream>>>(qb, kb, sinT, cosT, tqb, tkb);
    attn_score_kernel<<<kB * kNH * 32, 256, 0, stream>>>(qb, kb, tqb, tkb, tree_score, gateb, leaf_idx, attn);
    attn_ctx_kernel<<<kB * kNH * 16, 256, 0, stream>>>(attn, vb, ctx);
    gemm_kernel<2><<<dim3(kH / 128, kM / 128), 256, 0, stream>>>(ctx, Wo_i, bo + i * kH, x, kH, kH, 1.f);
    ln_kernel<<<kM, 256, 0, stream>>>(x, ln2_g + i * kH, ln2_b + i * kH, h);
    gemm_kernel<3><<<dim3(kDFF / 128, kM / 128), 256, 0, stream>>>(h, W1_i, b1 + i * kDFF, ffn, kH, kDFF, 1.f);
    gemm_kernel<2><<<dim3(kH / 128, kM / 128), 256, 0, stream>>>(ffn, W2_i, b2 + i * kH, x, kDFF, kH, 1.f);
  }
}

// Round 3
// 4827.631 us; speedup vs baseline: 2.3230x; 2.3230x over previous
//
#include <hip/hip_runtime.h>
#include <math.h>

constexpr int kB = 4;
constexpr int kL = 512;
constexpr int kH = 1024;
constexpr int kNH = 16;
constexpr int kNL = 4;
constexpr int kDK = 64;
constexpr int kDFF = 4096;
constexpr int kM = kB * kL;  // 2048
constexpr float kNEG = -1e18f;
constexpr float kInvSqrt2 = 0.70710678118654752440f;

typedef unsigned short ushort_t;
typedef short bf16x8 __attribute__((ext_vector_type(8)));
typedef float f32x4 __attribute__((ext_vector_type(4)));

__device__ inline ushort_t f2bf(float f) {
  union { float f; unsigned u; } v;
  v.f = f;
  unsigned r = v.u + 0x7fffu + ((v.u >> 16) & 1u);
  return (ushort_t)(r >> 16);
}
__device__ inline float bf2f(ushort_t h) {
  union { unsigned u; float f; } v;
  v.u = ((unsigned)h) << 16;
  return v.f;
}

// ---------------------------------------------------------------- sin/cos
__global__ __launch_bounds__(256) void sincos_kernel(const int* __restrict__ leaf_idx,
                                                     float* __restrict__ sinT,
                                                     float* __restrict__ cosT) {
  int idx = blockIdx.x * 256 + threadIdx.x;  // kB*kL*32
  int d = idx & 31;
  int bl = idx >> 5;
  float pos = (float)leaf_idx[bl];
  float freq = expf(-(float)d * (9.210340371976184f / 32.f));
  float ang = pos * freq;
  sinT[idx] = sinf(ang);
  cosT[idx] = cosf(ang);
}

// ---------------------------------------------------------------- layernorm (f32 in, bf16 out)
__global__ __launch_bounds__(256) void ln_kernel(const float* __restrict__ x,
                                                 const float* __restrict__ g,
                                                 const float* __restrict__ b,
                                                 ushort_t* __restrict__ out) {
  int row = blockIdx.x;
  int t = threadIdx.x;
  const float4* xr = (const float4*)(x + (size_t)row * kH);
  float4 v = xr[t];
  float s = v.x + v.y + v.z + v.w;
  float ss = v.x * v.x + v.y * v.y + v.z * v.z + v.w * v.w;
#pragma unroll
  for (int o = 32; o > 0; o >>= 1) {
    s += __shfl_down(s, o);
    ss += __shfl_down(ss, o);
  }
  __shared__ float redS[4], redQ[4];
  __shared__ float muS, invS;
  int w = t >> 6;
  if ((t & 63) == 0) {
    redS[w] = s;
    redQ[w] = ss;
  }
  __syncthreads();
  if (t == 0) {
    float S = redS[0] + redS[1] + redS[2] + redS[3];
    float Q = redQ[0] + redQ[1] + redQ[2] + redQ[3];
    float mu = S * (1.f / kH);
    float var = Q * (1.f / kH) - mu * mu;
    muS = mu;
    invS = rsqrtf(var + 1e-5f);
  }
  __syncthreads();
  float mu = muS, inv = invS;
  float4 gv = ((const float4*)g)[t];
  float4 bv = ((const float4*)b)[t];
  ushort4 o;
  o.x = f2bf((v.x - mu) * inv * gv.x + bv.x);
  o.y = f2bf((v.y - mu) * inv * gv.y + bv.y);
  o.z = f2bf((v.z - mu) * inv * gv.z + bv.z);
  o.w = f2bf((v.w - mu) * inv * gv.w + bv.w);
  *(ushort4*)&out[(size_t)row * kH + t * 4] = o;
}

// ---------------------------------------------------------------- weight transpose+convert: W[K][N] f32 -> Wt[N][K] bf16
__global__ __launch_bounds__(256) void tconv_kernel(const float* __restrict__ W,
                                                    ushort_t* __restrict__ Wt, int K, int N) {
  __shared__ float tl[64][65];
  int t = threadIdx.x;
  int bx = blockIdx.x, by = blockIdx.y;  // bx over N/64, by over K/64
#pragma unroll
  for (int jj = 0; jj < 16; jj++) {
    int idx = jj * 256 + t;
    int r = idx >> 6, c = idx & 63;
    tl[r][c] = W[(size_t)(by * 64 + r) * N + bx * 64 + c];
  }
  __syncthreads();
#pragma unroll
  for (int jj = 0; jj < 16; jj++) {
    int idx = jj * 256 + t;
    int c2 = idx >> 6, r2 = idx & 63;
    Wt[(size_t)(bx * 64 + c2) * K + by * 64 + r2] = f2bf(tl[r2][c2]);
  }
}

// ---------------------------------------------------------------- bf16 MFMA GEMM (NT: A[M][K], Bt[N][K])
// EPI: 0 = fused QKV (write q/k/v transposed f32, scale q), 1 = residual add into f32 C, 2 = GELU -> bf16 C
template <int EPI>
__global__ __launch_bounds__(256) void mm_kernel(const ushort_t* __restrict__ A,
                                                 const ushort_t* __restrict__ Bt,
                                                 const float* __restrict__ b0,
                                                 const float* __restrict__ b1,
                                                 const float* __restrict__ b2,
                                                 float* __restrict__ Cf,
                                                 ushort_t* __restrict__ Cb, int K, int N) {
  __shared__ __align__(16) ushort_t ALds[2][4096];
  __shared__ __align__(16) ushort_t BLds[2][4096];
  int t = threadIdx.x;
  int wave = t >> 6, lane = t & 63;
  int wm = wave >> 1, wn = wave & 1;
  int row0 = blockIdx.y * 128, col0 = blockIdx.x * 128;

  f32x4 zero = {0.f, 0.f, 0.f, 0.f};
  f32x4 acc[4][4];
#pragma unroll
  for (int i = 0; i < 4; i++)
#pragma unroll
    for (int j = 0; j < 4; j++) acc[i][j] = zero;

  // staging: thread handles k-group g, tile-rows r0 and r0+64 (each 8 bf16 = 16B)
  int g = t & 3;
  int r0 = t >> 2;
  int r1 = r0 + 64;
  int lds0 = (((r0 >> 4) * 64) + g * 16 + (r0 & 15)) * 8;
  int lds1 = (((r1 >> 4) * 64) + g * 16 + (r1 & 15)) * 8;
  const ushort_t* Ap0 = A + (size_t)(row0 + r0) * K + g * 8;
  const ushort_t* Ap1 = A + (size_t)(row0 + r1) * K + g * 8;
  const ushort_t* Bp0 = Bt + (size_t)(col0 + r0) * K + g * 8;
  const ushort_t* Bp1 = Bt + (size_t)(col0 + r1) * K + g * 8;

  int nk = K >> 5;
  bf16x8 a0 = *(const bf16x8*)Ap0;
  bf16x8 a1 = *(const bf16x8*)Ap1;
  bf16x8 v0 = *(const bf16x8*)Bp0;
  bf16x8 v1 = *(const bf16x8*)Bp1;
  *(bf16x8*)&ALds[0][lds0] = a0;
  *(bf16x8*)&ALds[0][lds1] = a1;
  *(bf16x8*)&BLds[0][lds0] = v0;
  *(bf16x8*)&BLds[0][lds1] = v1;
  __syncthreads();
  int cur = 0;
  for (int kt = 0; kt < nk; kt++) {
    if (kt + 1 < nk) {
      int ko = (kt + 1) << 5;
      a0 = *(const bf16x8*)(Ap0 + ko);
      a1 = *(const bf16x8*)(Ap1 + ko);
      v0 = *(const bf16x8*)(Bp0 + ko);
      v1 = *(const bf16x8*)(Bp1 + ko);
    }
    bf16x8 af[4], bf[4];
#pragma unroll
    for (int i = 0; i < 4; i++) {
      af[i] = *(const bf16x8*)&ALds[cur][((wm * 4 + i) * 64 + lane) * 8];
      bf[i] = *(const bf16x8*)&BLds[cur][((wn * 4 + i) * 64 + lane) * 8];
    }
#pragma unroll
    for (int mi = 0; mi < 4; mi++)
#pragma unroll
      for (int ni = 0; ni < 4; ni++)
        acc[mi][ni] = __builtin_amdgcn_mfma_f32_16x16x32_bf16(af[mi], bf[ni], acc[mi][ni], 0, 0, 0);
    if (kt + 1 < nk) {
      __syncthreads();
      *(bf16x8*)&ALds[cur ^ 1][lds0] = a0;
      *(bf16x8*)&ALds[cur ^ 1][lds1] = a1;
      *(bf16x8*)&BLds[cur ^ 1][lds0] = v0;
      *(bf16x8*)&BLds[cur ^ 1][lds1] = v1;
      __syncthreads();
      cur ^= 1;
    }
  }

  int lrow = (lane >> 4) * 4;
  int lcol = lane & 15;
#pragma unroll
  for (int mi = 0; mi < 4; mi++) {
#pragma unroll
    for (int ni = 0; ni < 4; ni++) {
#pragma unroll
      for (int j = 0; j < 4; j++) {
        int rowg = row0 + wm * 64 + mi * 16 + lrow + j;
        int colg = col0 + wn * 64 + ni * 16 + lcol;
        float val = acc[mi][ni][j];
        if (EPI == 0) {
          int which = colg >> 10;
          int cc = colg & 1023;
          const float* bp = which == 0 ? b0 : (which == 1 ? b1 : b2);
          val += bp[cc];
          if (which == 0) val *= 0.125f;
          int bb_ = rowg >> 9, l = rowg & 511;
          int hd = cc >> 6, d = cc & 63;
          Cf[(size_t)which * 2097152 + ((size_t)(bb_ * kNH + hd) * kL + l) * kDK + d] = val;
        } else if (EPI == 1) {
          val += b0[colg];
          Cf[(size_t)rowg * N + colg] += val;
        } else {
          val += b0[colg];
          val = 0.5f * val * (1.f + erff(val * kInvSqrt2));
          Cb[(size_t)rowg * N + colg] = f2bf(val);
        }
      }
    }
  }
}

// ---------------------------------------------------------------- gate (bf16 h)
__global__ __launch_bounds__(256) void gate_kernel(const ushort_t* __restrict__ h,
                                                   const float* __restrict__ Wg,
                                                   const float* __restrict__ bg,
                                                   const int* __restrict__ leaf_idx,
                                                   float* __restrict__ gate) {
  int row = blockIdx.x;
  int t = threadIdx.x;
  int o = t & 15, s = t >> 4;
  const ushort_t* hr = h + (size_t)row * kH;
  float acc = 0.f;
#pragma unroll 4
  for (int k = s * 64; k < s * 64 + 64; k++) acc = fmaf(bf2f(hr[k]), Wg[k * kNH + o], acc);
  __shared__ float red[16][17];
  red[s][o] = acc;
  __syncthreads();
  if (t < 16) {
    float z = bg[t];
#pragma unroll
    for (int i = 0; i < 16; i++) z += red[i][t];
    float gv = 1.f / (1.f + expf(-z));
    if (leaf_idx[row] == 0) gv = 1.f;
    int b = row >> 9, l = row & 511;
    gate[((size_t)(b * kNH + t)) * kL + l] = gv;
  }
}

// ---------------------------------------------------------------- rotary
__global__ __launch_bounds__(256) void rotary_kernel(const float* __restrict__ q,
                                                     const float* __restrict__ k,
                                                     const float* __restrict__ sinT,
                                                     const float* __restrict__ cosT,
                                                     float* __restrict__ tq,
                                                     float* __restrict__ tk) {
  int idx = blockIdx.x * 256 + threadIdx.x;  // kB*kNH*kL*32
  int d2 = idx & 31;
  int l = (idx >> 5) & (kL - 1);
  int hh = (idx >> 14) & (kNH - 1);
  int b = idx >> 18;
  size_t base = ((size_t)(b * kNH + hh) * kL + l) * kDK + d2 * 2;
  int sidx = (b * kL + l) * 32 + d2;
  float sn = sinT[sidx], cs = cosT[sidx];
  float x1 = q[base], x2 = q[base + 1];
  tq[base] = x1 * cs - x2 * sn;
  tq[base + 1] = x2 * cs + x1 * sn;
  x1 = k[base];
  x2 = k[base + 1];
  tk[base] = x1 * cs - x2 * sn;
  tk[base + 1] = x2 * cs + x1 * sn;
}

// ---------------------------------------------------------------- attention scores (streaming, spill-free)
// writes raw tree scores (st) / leaf scores (sl) + per-row maxes (mtb/mlb)
__global__ __launch_bounds__(256) void attn_score_kernel(
    const float* __restrict__ q, const float* __restrict__ k,
    const float* __restrict__ tq, const float* __restrict__ tk,
    const float* __restrict__ tree_score, const int* __restrict__ leaf_idx,
    float* __restrict__ st, float* __restrict__ sl,
    float* __restrict__ mtb, float* __restrict__ mlb) {
  __shared__ __align__(16) float kt[64][68];
  __shared__ __align__(16) float tkt[64][68];
  __shared__ __align__(16) float qt[16][68];
  __shared__ __align__(16) float tqt[16][68];

  int t = threadIdx.x;
  int blk = blockIdx.x;  // ((b*NH+h)*32 + qtile)
  int qtile = blk & 31;
  int bh = blk >> 5;
  int b = bh >> 4;
  int q0 = qtile * 16;
  size_t headoff = (size_t)bh * kL * kDK;

  {
    int r = t >> 4, c4 = t & 15;
    *(float4*)&qt[r][c4 * 4] = *(const float4*)(q + headoff + (size_t)(q0 + r) * kDK + c4 * 4);
    *(float4*)&tqt[r][c4 * 4] = *(const float4*)(tq + headoff + (size_t)(q0 + r) * kDK + c4 * 4);
  }

  int wave = t >> 6, lane = t & 63;
  float mt[4] = {-1e30f, -1e30f, -1e30f, -1e30f};
  float ml[4] = {-1e30f, -1e30f, -1e30f, -1e30f};

  for (int tile = 0; tile < 8; tile++) {
    int kt0 = tile * 64;
    __syncthreads();
    {
      int c4 = t & 15;
#pragma unroll
      for (int jj = 0; jj < 4; jj++) {
        int r = (t >> 4) + jj * 16;
        *(float4*)&kt[r][c4 * 4] = *(const float4*)(k + headoff + (size_t)(kt0 + r) * kDK + c4 * 4);
        *(float4*)&tkt[r][c4 * 4] = *(const float4*)(tk + headoff + (size_t)(kt0 + r) * kDK + c4 * 4);
      }
    }
    __syncthreads();

    float at[4] = {0.f, 0.f, 0.f, 0.f};
    float al[4] = {0.f, 0.f, 0.f, 0.f};
#pragma unroll
    for (int i4 = 0; i4 < 16; i4++) {
      float4 kv = *(const float4*)&kt[lane][i4 * 4];
      float4 tkv = *(const float4*)&tkt[lane][i4 * 4];
#pragma unroll
      for (int r = 0; r < 4; r++) {
        float4 qv = *(const float4*)&qt[wave * 4 + r][i4 * 4];
        float4 tqv = *(const float4*)&tqt[wave * 4 + r][i4 * 4];
        at[r] = fmaf(qv.x, kv.x, at[r]);
        at[r] = fmaf(qv.y, kv.y, at[r]);
        at[r] = fmaf(qv.z, kv.z, at[r]);
        at[r] = fmaf(qv.w, kv.w, at[r]);
        al[r] = fmaf(tqv.x, tkv.x, al[r]);
        al[r] = fmaf(tqv.y, tkv.y, al[r]);
        al[r] = fmaf(tqv.z, tkv.z, al[r]);
        al[r] = fmaf(tqv.w, tkv.w, al[r]);
      }
    }
    int kvld = (leaf_idx[b * kL + kt0 + lane] != 0);
#pragma unroll
    for (int r = 0; r < 4; r++) {
      int qg = q0 + wave * 4 + r;
      size_t rowbase = ((size_t)bh * kL + qg) * kL;
      float ts = tree_score[rowbase + kt0 + lane];
      float vt = kvld ? (at[r] + ts) * kInvSqrt2 : kNEG;
      float vl = kvld ? al[r] : kNEG;
      mt[r] = fmaxf(mt[r], vt);
      ml[r] = fmaxf(ml[r], vl);
      st[rowbase + kt0 + lane] = vt;
      sl[rowbase + kt0 + lane] = vl;
    }
  }
#pragma unroll
  for (int r = 0; r < 4; r++) {
#pragma unroll
    for (int o = 32; o > 0; o >>= 1) {
      mt[r] = fmaxf(mt[r], __shfl_xor(mt[r], o));
      ml[r] = fmaxf(ml[r], __shfl_xor(ml[r], o));
    }
    if (lane == 0) {
      int qg = q0 + wave * 4 + r;
      mtb[bh * kL + qg] = mt[r];
      mlb[bh * kL + qg] = ml[r];
    }
  }
}

// ---------------------------------------------------------------- softmax + gate blend (in-place on st)
__global__ __launch_bounds__(256) void blend_kernel(float* __restrict__ st,
                                                    const float* __restrict__ sl,
                                                    const float* __restrict__ mtb,
                                                    const float* __restrict__ mlb,
                                                    const float* __restrict__ gate) {
  int rowid = blockIdx.x * 4 + (threadIdx.x >> 6);
  int lane = threadIdx.x & 63;
  float* srow = st + (size_t)rowid * kL;
  const float* lrow = sl + (size_t)rowid * kL;
  float mt = mtb[rowid], ml = mlb[rowid], g = gate[rowid];
  float pt[8], pl[8];
  float sumt = 0.f, suml = 0.f;
#pragma unroll
  for (int j = 0; j < 8; j++) {
    pt[j] = expf(srow[j * 64 + lane] - mt);
    sumt += pt[j];
    pl[j] = expf(lrow[j * 64 + lane] - ml);
    suml += pl[j];
  }
#pragma unroll
  for (int o = 32; o > 0; o >>= 1) {
    sumt += __shfl_xor(sumt, o);
    suml += __shfl_xor(suml, o);
  }
  float it = g / sumt, il = (1.f - g) / suml;
#pragma unroll
  for (int j = 0; j < 8; j++) srow[j * 64 + lane] = pt[j] * it + pl[j] * il;
}

// ---------------------------------------------------------------- ctx = attn @ v (bf16 out)
__global__ __launch_bounds__(256) void attn_ctx_kernel(const float* __restrict__ attn,
                                                       const float* __restrict__ v,
                                                       ushort_t* __restrict__ ctx) {
  __shared__ __align__(16) float vt[64][68];
  __shared__ __align__(16) float at[32][68];
  int t = threadIdx.x;
  int blk = blockIdx.x;  // ((b*NH+h)*16 + q32)
  int q32 = blk & 15;
  int bh = blk >> 4;
  int q0 = q32 * 32;
  int wave = t >> 6, lane = t & 63;
  size_t headoff = (size_t)bh * kL * kDK;
  float acc[8] = {0.f, 0.f, 0.f, 0.f, 0.f, 0.f, 0.f, 0.f};
  for (int kt0 = 0; kt0 < kL; kt0 += 64) {
    __syncthreads();
    {
      int c4 = t & 15;
#pragma unroll
      for (int jj = 0; jj < 4; jj++) {
        int r = (t >> 4) + jj * 16;
        *(float4*)&vt[r][c4 * 4] = *(const float4*)(v + headoff + (size_t)(kt0 + r) * kDK + c4 * 4);
      }
#pragma unroll
      for (int jj = 0; jj < 2; jj++) {
        int idx = t + jj * 256;
        int r = idx >> 4, cc = idx & 15;
        *(float4*)&at[r][cc * 4] =
            *(const float4*)(attn + ((size_t)bh * kL + q0 + r) * kL + kt0 + cc * 4);
      }
    }
    __syncthreads();
#pragma unroll
    for (int kk = 0; kk < 64; kk += 4) {
      float v0 = vt[kk][lane], v1 = vt[kk + 1][lane], v2 = vt[kk + 2][lane], v3 = vt[kk + 3][lane];
#pragma unroll
      for (int r = 0; r < 8; r++) {
        float4 a = *(const float4*)&at[wave * 8 + r][kk];
        acc[r] = fmaf(a.x, v0, acc[r]);
        acc[r] = fmaf(a.y, v1, acc[r]);
        acc[r] = fmaf(a.z, v2, acc[r]);
        acc[r] = fmaf(a.w, v3, acc[r]);
      }
    }
  }
  int b = bh >> 4, hh = bh & 15;
#pragma unroll
  for (int r = 0; r < 8; r++) {
    int qg = q0 + wave * 8 + r;
    ctx[((size_t)b * kL + qg) * kH + hh * kDK + lane] = f2bf(acc[r]);
  }
}

// ---------------------------------------------------------------- launch
extern "C" void kernel_launch(void* const* d_in, const int* in_sizes, int n_in,
                              void* d_out, int out_size, void* d_ws, size_t ws_size,
                              hipStream_t stream) {
  (void)in_sizes;
  (void)n_in;
  (void)out_size;
  (void)ws_size;
  const float* content = (const float*)d_in[0];
  const float* tree_score = (const float*)d_in[1];
  const float* Wq = (const float*)d_in[2];
  const float* bq = (const float*)d_in[3];
  const float* Wk = (const float*)d_in[4];
  const float* bk = (const float*)d_in[5];
  const float* Wv = (const float*)d_in[6];
  const float* bv = (const float*)d_in[7];
  const float* Wo = (const float*)d_in[8];
  const float* bo = (const float*)d_in[9];
  const float* Wg = (const float*)d_in[10];
  const float* bg = (const float*)d_in[11];
  const float* W1 = (const float*)d_in[12];
  const float* b1 = (const float*)d_in[13];
  const float* W2 = (const float*)d_in[14];
  const float* b2 = (const float*)d_in[15];
  const float* ln1_g = (const float*)d_in[16];
  const float* ln1_b = (const float*)d_in[17];
  const float* ln2_g = (const float*)d_in[18];
  const float* ln2_b = (const float*)d_in[19];
  // d_in[20] = mask (bool) — identical to leaf_idx==0, unused
  const int* leaf_idx = (const int*)d_in[21];

  float* x = (float*)d_out;
  float* p = (float*)d_ws;
  float* sinT = p; p += kB * kL * 32;
  float* cosT = p; p += kB * kL * 32;
  float* gateb = p; p += kB * kNH * kL;
  float* mtb = p; p += kB * kNH * kL;
  float* mlb = p; p += kB * kNH * kL;
  ushort_t* h_bf = (ushort_t*)p; p += (size_t)kM * kH / 2;
  ushort_t* ctx_bf = (ushort_t*)p; p += (size_t)kM * kH / 2;
  float* qkv = p; p += (size_t)3 * kM * kH;  // q | k | v, each [B,NH,L,DK]
  float* tqb = p; p += (size_t)kM * kH;
  float* tkb = p; p += (size_t)kM * kH;
  ushort_t* WTqkv = (ushort_t*)p; p += (size_t)3 * kH * kH / 2;  // [3072][1024] bf16
  ushort_t* WTo = (ushort_t*)p; p += (size_t)kH * kH / 2;        // [1024][1024]
  ushort_t* WT1 = (ushort_t*)p; p += (size_t)kH * kDFF / 2;      // [4096][1024]
  ushort_t* WT2 = (ushort_t*)p; p += (size_t)kDFF * kH / 2;      // [1024][4096]
  float* st = p; p += (size_t)kB * kNH * kL * kL;
  float* sl = p;  // kB*kNH*kL*kL floats
  ushort_t* ffn_bf = (ushort_t*)sl;  // aliased: sl dead after blend_kernel

  float* qb = qkv;
  float* kb = qkv + (size_t)kM * kH;
  float* vb = qkv + (size_t)2 * kM * kH;

  hipMemcpyAsync(x, content, (size_t)kM * kH * sizeof(float), hipMemcpyDeviceToDevice, stream);
  sincos_kernel<<<kB * kL * 32 / 256, 256, 0, stream>>>(leaf_idx, sinT, cosT);

  for (int i = 0; i < kNL; i++) {
    // per-layer weight convert+transpose into bf16 [N][K]
    tconv_kernel<<<dim3(16, 16), 256, 0, stream>>>(Wq + (size_t)i * kH * kH, WTqkv, kH, kH);
    tconv_kernel<<<dim3(16, 16), 256, 0, stream>>>(Wk + (size_t)i * kH * kH, WTqkv + (size_t)kH * kH, kH, kH);
    tconv_kernel<<<dim3(16, 16), 256, 0, stream>>>(Wv + (size_t)i * kH * kH, WTqkv + (size_t)2 * kH * kH, kH, kH);
    tconv_kernel<<<dim3(16, 16), 256, 0, stream>>>(Wo + (size_t)i * kH * kH, WTo, kH, kH);
    tconv_kernel<<<dim3(64, 16), 256, 0, stream>>>(W1 + (size_t)i * kH * kDFF, WT1, kH, kDFF);
    tconv_kernel<<<dim3(16, 64), 256, 0, stream>>>(W2 + (size_t)i * kDFF * kH, WT2, kDFF, kH);

    ln_kernel<<<kM, 256, 0, stream>>>(x, ln1_g + i * kH, ln1_b + i * kH, h_bf);
    mm_kernel<0><<<dim3(24, 16), 256, 0, stream>>>(h_bf, WTqkv, bq + i * kH, bk + i * kH,
                                                   bv + i * kH, qkv, nullptr, kH, 3 * kH);
    gate_kernel<<<kM, 256, 0, stream>>>(h_bf, Wg + (size_t)i * kH * kNH, bg + i * kNH, leaf_idx, gateb);
    rotary_kernel<<<kB * kNH * kL * 32 / 256, 256, 0, stream>>>(qb, kb, sinT, cosT, tqb, tkb);
    attn_score_kernel<<<kB * kNH * 32, 256, 0, stream>>>(qb, kb, tqb, tkb, tree_score, leaf_idx,
                                                         st, sl, mtb, mlb);
    blend_kernel<<<kB * kNH * kL / 4, 256, 0, stream>>>(st, sl, mtb, mlb, gateb);
    attn_ctx_kernel<<<kB * kNH * 16, 256, 0, stream>>>(st, vb, ctx_bf);
    mm_kernel<1><<<dim3(8, 16), 256, 0, stream>>>(ctx_bf, WTo, bo + i * kH, nullptr, nullptr,
                                                  x, nullptr, kH, kH);
    ln_kernel<<<kM, 256, 0, stream>>>(x, ln2_g + i * kH, ln2_b + i * kH, h_bf);
    mm_kernel<2><<<dim3(32, 16), 256, 0, stream>>>(h_bf, WT1, b1 + i * kDFF, nullptr, nullptr,
                                                   nullptr, ffn_bf, kH, kDFF);
    mm_kernel<1><<<dim3(8, 16), 256, 0, stream>>>(ffn_bf, WT2, b2 + i * kH, nullptr, nullptr,
                                                  x, nullptr, kDFF, kH);
  }
}

// Round 4
// 1633.932 us; speedup vs baseline: 6.8636x; 2.9546x over previous
//
#include <hip/hip_runtime.h>
#include <math.h>

constexpr int kB = 4;
constexpr int kL = 512;
constexpr int kH = 1024;
constexpr int kNH = 16;
constexpr int kNL = 4;
constexpr int kDK = 64;
constexpr int kDFF = 4096;
constexpr int kM = kB * kL;  // 2048
constexpr float kNEG = -1e18f;
constexpr float kInvSqrt2 = 0.70710678118654752440f;

typedef unsigned short ushort_t;
typedef short bf16x8 __attribute__((ext_vector_type(8)));
typedef float f32x4 __attribute__((ext_vector_type(4)));

__device__ inline ushort_t f2bf(float f) {
  union { float f; unsigned u; } v;
  v.f = f;
  unsigned r = v.u + 0x7fffu + ((v.u >> 16) & 1u);
  return (ushort_t)(r >> 16);
}
__device__ inline float bf2f(ushort_t h) {
  union { unsigned u; float f; } v;
  v.u = ((unsigned)h) << 16;
  return v.f;
}

// ---------------------------------------------------------------- sin/cos
__global__ __launch_bounds__(256) void sincos_kernel(const int* __restrict__ leaf_idx,
                                                     float* __restrict__ sinT,
                                                     float* __restrict__ cosT) {
  int idx = blockIdx.x * 256 + threadIdx.x;  // kB*kL*32
  int d = idx & 31;
  int bl = idx >> 5;
  float pos = (float)leaf_idx[bl];
  float freq = expf(-(float)d * (9.210340371976184f / 32.f));
  float ang = pos * freq;
  sinT[idx] = sinf(ang);
  cosT[idx] = cosf(ang);
}

// ---------------------------------------------------------------- layernorm (f32 in, bf16 out)
__global__ __launch_bounds__(256) void ln_kernel(const float* __restrict__ x,
                                                 const float* __restrict__ g,
                                                 const float* __restrict__ b,
                                                 ushort_t* __restrict__ out) {
  int row = blockIdx.x;
  int t = threadIdx.x;
  const float4* xr = (const float4*)(x + (size_t)row * kH);
  float4 v = xr[t];
  float s = v.x + v.y + v.z + v.w;
  float ss = v.x * v.x + v.y * v.y + v.z * v.z + v.w * v.w;
#pragma unroll
  for (int o = 32; o > 0; o >>= 1) {
    s += __shfl_down(s, o);
    ss += __shfl_down(ss, o);
  }
  __shared__ float redS[4], redQ[4];
  __shared__ float muS, invS;
  int w = t >> 6;
  if ((t & 63) == 0) {
    redS[w] = s;
    redQ[w] = ss;
  }
  __syncthreads();
  if (t == 0) {
    float S = redS[0] + redS[1] + redS[2] + redS[3];
    float Q = redQ[0] + redQ[1] + redQ[2] + redQ[3];
    float mu = S * (1.f / kH);
    float var = Q * (1.f / kH) - mu * mu;
    muS = mu;
    invS = rsqrtf(var + 1e-5f);
  }
  __syncthreads();
  float mu = muS, inv = invS;
  float4 gv = ((const float4*)g)[t];
  float4 bv = ((const float4*)b)[t];
  ushort4 o;
  o.x = f2bf((v.x - mu) * inv * gv.x + bv.x);
  o.y = f2bf((v.y - mu) * inv * gv.y + bv.y);
  o.z = f2bf((v.z - mu) * inv * gv.z + bv.z);
  o.w = f2bf((v.w - mu) * inv * gv.w + bv.w);
  *(ushort4*)&out[(size_t)row * kH + t * 4] = o;
}

// ---------------------------------------------------------------- weight transpose+convert: W[K][N] f32 -> Wt[N][K] bf16
__global__ __launch_bounds__(256) void tconv_kernel(const float* __restrict__ W,
                                                    ushort_t* __restrict__ Wt, int K, int N) {
  __shared__ float tl[64][65];
  int t = threadIdx.x;
  int bx = blockIdx.x, by = blockIdx.y;  // bx over N/64, by over K/64
#pragma unroll
  for (int jj = 0; jj < 16; jj++) {
    int idx = jj * 256 + t;
    int r = idx >> 6, c = idx & 63;
    tl[r][c] = W[(size_t)(by * 64 + r) * N + bx * 64 + c];
  }
  __syncthreads();
#pragma unroll
  for (int jj = 0; jj < 16; jj++) {
    int idx = jj * 256 + t;
    int c2 = idx >> 6, r2 = idx & 63;
    Wt[(size_t)(bx * 64 + c2) * K + by * 64 + r2] = f2bf(tl[r2][c2]);
  }
}

// ---------------------------------------------------------------- bf16 MFMA GEMM (NT: A[M][K], Bt[N][K])
// EPI: 0 = fused QKV (q,k f32 transposed + scale q; v -> bf16 [B,NH,DK,L]),
//      1 = residual add into f32 C, 2 = GELU -> bf16 C
template <int EPI>
__global__ __launch_bounds__(256) void mm_kernel(const ushort_t* __restrict__ A,
                                                 const ushort_t* __restrict__ Bt,
                                                 const float* __restrict__ b0,
                                                 const float* __restrict__ b1,
                                                 const float* __restrict__ b2,
                                                 float* __restrict__ Cf,
                                                 ushort_t* __restrict__ Cb, int K, int N) {
  __shared__ __align__(16) ushort_t ALds[2][4096];
  __shared__ __align__(16) ushort_t BLds[2][4096];
  int t = threadIdx.x;
  int wave = t >> 6, lane = t & 63;
  int wm = wave >> 1, wn = wave & 1;
  int row0 = blockIdx.y * 128, col0 = blockIdx.x * 128;

  f32x4 zero = {0.f, 0.f, 0.f, 0.f};
  f32x4 acc[4][4];
#pragma unroll
  for (int i = 0; i < 4; i++)
#pragma unroll
    for (int j = 0; j < 4; j++) acc[i][j] = zero;

  int g = t & 3;
  int r0 = t >> 2;
  int r1 = r0 + 64;
  int lds0 = (((r0 >> 4) * 64) + g * 16 + (r0 & 15)) * 8;
  int lds1 = (((r1 >> 4) * 64) + g * 16 + (r1 & 15)) * 8;
  const ushort_t* Ap0 = A + (size_t)(row0 + r0) * K + g * 8;
  const ushort_t* Ap1 = A + (size_t)(row0 + r1) * K + g * 8;
  const ushort_t* Bp0 = Bt + (size_t)(col0 + r0) * K + g * 8;
  const ushort_t* Bp1 = Bt + (size_t)(col0 + r1) * K + g * 8;

  int nk = K >> 5;
  bf16x8 a0 = *(const bf16x8*)Ap0;
  bf16x8 a1 = *(const bf16x8*)Ap1;
  bf16x8 v0 = *(const bf16x8*)Bp0;
  bf16x8 v1 = *(const bf16x8*)Bp1;
  *(bf16x8*)&ALds[0][lds0] = a0;
  *(bf16x8*)&ALds[0][lds1] = a1;
  *(bf16x8*)&BLds[0][lds0] = v0;
  *(bf16x8*)&BLds[0][lds1] = v1;
  __syncthreads();
  int cur = 0;
  for (int kt = 0; kt < nk; kt++) {
    if (kt + 1 < nk) {
      int ko = (kt + 1) << 5;
      a0 = *(const bf16x8*)(Ap0 + ko);
      a1 = *(const bf16x8*)(Ap1 + ko);
      v0 = *(const bf16x8*)(Bp0 + ko);
      v1 = *(const bf16x8*)(Bp1 + ko);
    }
    bf16x8 af[4], bf[4];
#pragma unroll
    for (int i = 0; i < 4; i++) {
      af[i] = *(const bf16x8*)&ALds[cur][((wm * 4 + i) * 64 + lane) * 8];
      bf[i] = *(const bf16x8*)&BLds[cur][((wn * 4 + i) * 64 + lane) * 8];
    }
#pragma unroll
    for (int mi = 0; mi < 4; mi++)
#pragma unroll
      for (int ni = 0; ni < 4; ni++)
        acc[mi][ni] = __builtin_amdgcn_mfma_f32_16x16x32_bf16(af[mi], bf[ni], acc[mi][ni], 0, 0, 0);
    if (kt + 1 < nk) {
      __syncthreads();
      *(bf16x8*)&ALds[cur ^ 1][lds0] = a0;
      *(bf16x8*)&ALds[cur ^ 1][lds1] = a1;
      *(bf16x8*)&BLds[cur ^ 1][lds0] = v0;
      *(bf16x8*)&BLds[cur ^ 1][lds1] = v1;
      __syncthreads();
      cur ^= 1;
    }
  }

  int lrow = (lane >> 4) * 4;
  int lcol = lane & 15;
#pragma unroll
  for (int mi = 0; mi < 4; mi++) {
#pragma unroll
    for (int ni = 0; ni < 4; ni++) {
#pragma unroll
      for (int j = 0; j < 4; j++) {
        int rowg = row0 + wm * 64 + mi * 16 + lrow + j;
        int colg = col0 + wn * 64 + ni * 16 + lcol;
        float val = acc[mi][ni][j];
        if (EPI == 0) {
          int which = colg >> 10;
          int cc = colg & 1023;
          const float* bp = which == 0 ? b0 : (which == 1 ? b1 : b2);
          val += bp[cc];
          int bb_ = rowg >> 9, l = rowg & 511;
          int hd = cc >> 6, d = cc & 63;
          if (which == 2) {
            // v -> bf16 transposed [B,NH,DK,L]
            Cb[((size_t)(bb_ * kNH + hd) * kDK + d) * kL + l] = f2bf(val);
          } else {
            if (which == 0) val *= 0.125f;
            Cf[(size_t)which * 2097152 + ((size_t)(bb_ * kNH + hd) * kL + l) * kDK + d] = val;
          }
        } else if (EPI == 1) {
          val += b0[colg];
          Cf[(size_t)rowg * N + colg] += val;
        } else {
          val += b0[colg];
          val = 0.5f * val * (1.f + erff(val * kInvSqrt2));
          Cb[(size_t)rowg * N + colg] = f2bf(val);
        }
      }
    }
  }
}

// ---------------------------------------------------------------- gate (bf16 h)
__global__ __launch_bounds__(256) void gate_kernel(const ushort_t* __restrict__ h,
                                                   const float* __restrict__ Wg,
                                                   const float* __restrict__ bg,
                                                   const int* __restrict__ leaf_idx,
                                                   float* __restrict__ gate) {
  int row = blockIdx.x;
  int t = threadIdx.x;
  int o = t & 15, s = t >> 4;
  const ushort_t* hr = h + (size_t)row * kH;
  float acc = 0.f;
#pragma unroll 4
  for (int k = s * 64; k < s * 64 + 64; k++) acc = fmaf(bf2f(hr[k]), Wg[k * kNH + o], acc);
  __shared__ float red[16][17];
  red[s][o] = acc;
  __syncthreads();
  if (t < 16) {
    float z = bg[t];
#pragma unroll
    for (int i = 0; i < 16; i++) z += red[i][t];
    float gv = 1.f / (1.f + expf(-z));
    if (leaf_idx[row] == 0) gv = 1.f;
    int b = row >> 9, l = row & 511;
    gate[((size_t)(b * kNH + t)) * kL + l] = gv;
  }
}

// ---------------------------------------------------------------- rotary: f32 q,k -> bf16 q, rotq, k, rotk
__global__ __launch_bounds__(256) void rotary_kernel(const float* __restrict__ q,
                                                     const float* __restrict__ k,
                                                     const float* __restrict__ sinT,
                                                     const float* __restrict__ cosT,
                                                     ushort_t* __restrict__ qo,
                                                     ushort_t* __restrict__ tqo,
                                                     ushort_t* __restrict__ ko,
                                                     ushort_t* __restrict__ tko) {
  int idx = blockIdx.x * 256 + threadIdx.x;  // kB*kNH*kL*32
  int d2 = idx & 31;
  int l = (idx >> 5) & (kL - 1);
  int hh = (idx >> 14) & (kNH - 1);
  int b = idx >> 18;
  size_t base = ((size_t)(b * kNH + hh) * kL + l) * kDK + d2 * 2;
  int sidx = (b * kL + l) * 32 + d2;
  float sn = sinT[sidx], cs = cosT[sidx];
  float x1 = q[base], x2 = q[base + 1];
  qo[base] = f2bf(x1);
  qo[base + 1] = f2bf(x2);
  tqo[base] = f2bf(x1 * cs - x2 * sn);
  tqo[base + 1] = f2bf(x2 * cs + x1 * sn);
  x1 = k[base];
  x2 = k[base + 1];
  ko[base] = f2bf(x1);
  ko[base + 1] = f2bf(x2);
  tko[base] = f2bf(x1 * cs - x2 * sn);
  tko[base + 1] = f2bf(x2 * cs + x1 * sn);
}

// ---------------------------------------------------------------- fused flash attention
// block = (b, h, 64-q-rows); 4 waves, wave owns 16 q rows. Dual online softmax
// (tree/leaf), MFMA QK^T + PV, gate blend. No __syncthreads (wave-private LDS).
__global__ __launch_bounds__(256) void fattn_kernel(
    const ushort_t* __restrict__ qbf, const ushort_t* __restrict__ tqbf,
    const ushort_t* __restrict__ kbf, const ushort_t* __restrict__ tkbf,
    const ushort_t* __restrict__ vT, const float* __restrict__ tree_score,
    const float* __restrict__ gateb, const int* __restrict__ leaf_idx,
    ushort_t* __restrict__ ctx) {
  __shared__ __align__(16) ushort_t PL[4][2048];  // per-wave 16x128 bf16 P, A-frag layout
  int t = threadIdx.x;
  int wave = t >> 6, lane = t & 63;
  int g16 = lane >> 4, c16 = lane & 15;
  int blk = blockIdx.x;  // ((b*NH+h)*8 + qt)
  int qt = blk & 7, bh = blk >> 3, b = bh >> 4;
  int q0 = qt * 64 + wave * 16;
  size_t hoff = (size_t)bh * kL * kDK;
  const ushort_t* vTh = vT + (size_t)bh * kDK * kL;
  const float* tsrow = tree_score + ((size_t)bh * kL + q0) * kL;

  // Q fragments (rows q0+c16, k-dim = kb*32 + g16*8)
  bf16x8 aq[2], atq[2];
#pragma unroll
  for (int kb = 0; kb < 2; kb++) {
    size_t off = hoff + (size_t)(q0 + c16) * kDK + kb * 32 + g16 * 8;
    aq[kb] = *(const bf16x8*)(qbf + off);
    atq[kb] = *(const bf16x8*)(tqbf + off);
  }
  int qv[4];
#pragma unroll
  for (int j = 0; j < 4; j++) qv[j] = leaf_idx[b * kL + q0 + g16 * 4 + j] != 0;

  f32x4 zero = {0.f, 0.f, 0.f, 0.f};
  f32x4 ot[4], ol[4];
  float mT[4], sT[4], mL[4], sL[4];
#pragma unroll
  for (int d = 0; d < 4; d++) { ot[d] = zero; ol[d] = zero; }
#pragma unroll
  for (int j = 0; j < 4; j++) { mT[j] = -1e30f; sT[j] = 0.f; mL[j] = -1e30f; sL[j] = 0.f; }

  for (int kt0 = 0; kt0 < kL; kt0 += 128) {
    int kv_ok[8];
#pragma unroll
    for (int cb = 0; cb < 8; cb++)
      kv_ok[cb] = leaf_idx[b * kL + kt0 + cb * 16 + c16] != 0;

    // ================= tree pass =================
    {
      f32x4 sc[8];
#pragma unroll
      for (int cb = 0; cb < 8; cb++) {
        sc[cb] = zero;
#pragma unroll
        for (int kb = 0; kb < 2; kb++) {
          bf16x8 kf = *(const bf16x8*)(kbf + hoff + (size_t)(kt0 + cb * 16 + c16) * kDK + kb * 32 + g16 * 8);
          sc[cb] = __builtin_amdgcn_mfma_f32_16x16x32_bf16(aq[kb], kf, sc[cb], 0, 0, 0);
        }
      }
      float tm[4] = {-1e30f, -1e30f, -1e30f, -1e30f};
#pragma unroll
      for (int cb = 0; cb < 8; cb++) {
#pragma unroll
        for (int j = 0; j < 4; j++) {
          float ts = tsrow[(size_t)(g16 * 4 + j) * kL + kt0 + cb * 16 + c16];
          float v_ = kv_ok[cb] ? (sc[cb][j] + ts) * kInvSqrt2 : kNEG;
          sc[cb][j] = v_;
          tm[j] = fmaxf(tm[j], v_);
        }
      }
#pragma unroll
      for (int j = 0; j < 4; j++) {
#pragma unroll
        for (int o = 8; o > 0; o >>= 1) tm[j] = fmaxf(tm[j], __shfl_xor(tm[j], o));
        float mn = fmaxf(mT[j], tm[j]);
        float scl = __expf(mT[j] - mn);
        mT[j] = mn;
        sT[j] *= scl;
#pragma unroll
        for (int d = 0; d < 4; d++) ot[d][j] *= scl;
      }
      float rs[4] = {0.f, 0.f, 0.f, 0.f};
#pragma unroll
      for (int cb = 0; cb < 8; cb++) {
#pragma unroll
        for (int j = 0; j < 4; j++) {
          float pv = __expf(sc[cb][j] - mT[j]);
          rs[j] += pv;
          int k_ = cb * 16 + c16;
          PL[wave][(k_ >> 3) * 128 + (g16 * 4 + j) * 8 + (k_ & 7)] = f2bf(pv);
        }
      }
#pragma unroll
      for (int j = 0; j < 4; j++) {
#pragma unroll
        for (int o = 8; o > 0; o >>= 1) rs[j] += __shfl_xor(rs[j], o);
        sT[j] += rs[j];
      }
#pragma unroll
      for (int d = 0; d < 4; d++) {
        f32x4 o_ = ot[d];
#pragma unroll
        for (int kb2 = 0; kb2 < 4; kb2++) {
          bf16x8 pa = *(const bf16x8*)&PL[wave][(kb2 * 4 + g16) * 128 + c16 * 8];
          bf16x8 vf = *(const bf16x8*)(vTh + (size_t)(d * 16 + c16) * kL + kt0 + kb2 * 32 + g16 * 8);
          o_ = __builtin_amdgcn_mfma_f32_16x16x32_bf16(pa, vf, o_, 0, 0, 0);
        }
        ot[d] = o_;
      }
    }

    // ================= leaf pass =================
    {
      f32x4 sc[8];
#pragma unroll
      for (int cb = 0; cb < 8; cb++) {
        sc[cb] = zero;
#pragma unroll
        for (int kb = 0; kb < 2; kb++) {
          bf16x8 kf = *(const bf16x8*)(tkbf + hoff + (size_t)(kt0 + cb * 16 + c16) * kDK + kb * 32 + g16 * 8);
          sc[cb] = __builtin_amdgcn_mfma_f32_16x16x32_bf16(atq[kb], kf, sc[cb], 0, 0, 0);
        }
      }
      float tm[4] = {-1e30f, -1e30f, -1e30f, -1e30f};
#pragma unroll
      for (int cb = 0; cb < 8; cb++) {
#pragma unroll
        for (int j = 0; j < 4; j++) {
          float v_ = (kv_ok[cb] && qv[j]) ? sc[cb][j] : kNEG;
          sc[cb][j] = v_;
          tm[j] = fmaxf(tm[j], v_);
        }
      }
#pragma unroll
      for (int j = 0; j < 4; j++) {
#pragma unroll
        for (int o = 8; o > 0; o >>= 1) tm[j] = fmaxf(tm[j], __shfl_xor(tm[j], o));
        float mn = fmaxf(mL[j], tm[j]);
        float scl = __expf(mL[j] - mn);
        mL[j] = mn;
        sL[j] *= scl;
#pragma unroll
        for (int d = 0; d < 4; d++) ol[d][j] *= scl;
      }
      float rs[4] = {0.f, 0.f, 0.f, 0.f};
#pragma unroll
      for (int cb = 0; cb < 8; cb++) {
#pragma unroll
        for (int j = 0; j < 4; j++) {
          float pv = __expf(sc[cb][j] - mL[j]);
          rs[j] += pv;
          int k_ = cb * 16 + c16;
          PL[wave][(k_ >> 3) * 128 + (g16 * 4 + j) * 8 + (k_ & 7)] = f2bf(pv);
        }
      }
#pragma unroll
      for (int j = 0; j < 4; j++) {
#pragma unroll
        for (int o = 8; o > 0; o >>= 1) rs[j] += __shfl_xor(rs[j], o);
        sL[j] += rs[j];
      }
#pragma unroll
      for (int d = 0; d < 4; d++) {
        f32x4 o_ = ol[d];
#pragma unroll
        for (int kb2 = 0; kb2 < 4; kb2++) {
          bf16x8 pa = *(const bf16x8*)&PL[wave][(kb2 * 4 + g16) * 128 + c16 * 8];
          bf16x8 vf = *(const bf16x8*)(vTh + (size_t)(d * 16 + c16) * kL + kt0 + kb2 * 32 + g16 * 8);
          o_ = __builtin_amdgcn_mfma_f32_16x16x32_bf16(pa, vf, o_, 0, 0, 0);
        }
        ol[d] = o_;
      }
    }
  }

  // epilogue: blend + write ctx [B,L,H]
#pragma unroll
  for (int j = 0; j < 4; j++) {
    int qg = q0 + g16 * 4 + j;
    float g = gateb[(size_t)bh * kL + qg];
    float wt = g / sT[j], wl = (1.f - g) / sL[j];
#pragma unroll
    for (int d = 0; d < 4; d++) {
      float val = ot[d][j] * wt + ol[d][j] * wl;
      ctx[((size_t)b * kL + qg) * kH + (bh & 15) * kDK + d * 16 + c16] = f2bf(val);
    }
  }
}

// ---------------------------------------------------------------- launch
extern "C" void kernel_launch(void* const* d_in, const int* in_sizes, int n_in,
                              void* d_out, int out_size, void* d_ws, size_t ws_size,
                              hipStream_t stream) {
  (void)in_sizes;
  (void)n_in;
  (void)out_size;
  (void)ws_size;
  const float* content = (const float*)d_in[0];
  const float* tree_score = (const float*)d_in[1];
  const float* Wq = (const float*)d_in[2];
  const float* bq = (const float*)d_in[3];
  const float* Wk = (const float*)d_in[4];
  const float* bk = (const float*)d_in[5];
  const float* Wv = (const float*)d_in[6];
  const float* bv = (const float*)d_in[7];
  const float* Wo = (const float*)d_in[8];
  const float* bo = (const float*)d_in[9];
  const float* Wg = (const float*)d_in[10];
  const float* bg = (const float*)d_in[11];
  const float* W1 = (const float*)d_in[12];
  const float* b1 = (const float*)d_in[13];
  const float* W2 = (const float*)d_in[14];
  const float* b2 = (const float*)d_in[15];
  const float* ln1_g = (const float*)d_in[16];
  const float* ln1_b = (const float*)d_in[17];
  const float* ln2_g = (const float*)d_in[18];
  const float* ln2_b = (const float*)d_in[19];
  // d_in[20] = mask (bool) — identical to leaf_idx==0, unused
  const int* leaf_idx = (const int*)d_in[21];

  float* x = (float*)d_out;
  float* p = (float*)d_ws;
  float* sinT = p; p += kB * kL * 32;
  float* cosT = p; p += kB * kL * 32;
  float* gateb = p; p += kB * kNH * kL;
  float* qkf = p; p += (size_t)2 * kM * kH;  // q | k f32, [B,NH,L,DK]
  ushort_t* h_bf = (ushort_t*)p; p += (size_t)kM * kH / 2;
  ushort_t* ctx_bf = (ushort_t*)p; p += (size_t)kM * kH / 2;
  ushort_t* qbf = (ushort_t*)p; p += (size_t)kM * kH / 2;
  ushort_t* tqbf = (ushort_t*)p; p += (size_t)kM * kH / 2;
  ushort_t* kbf = (ushort_t*)p; p += (size_t)kM * kH / 2;
  ushort_t* tkbf = (ushort_t*)p; p += (size_t)kM * kH / 2;
  ushort_t* vT = (ushort_t*)p; p += (size_t)kM * kH / 2;  // [B,NH,DK,L] bf16
  ushort_t* WTqkv = (ushort_t*)p; p += (size_t)3 * kH * kH / 2;
  ushort_t* WTo = (ushort_t*)p; p += (size_t)kH * kH / 2;
  ushort_t* WT1 = (ushort_t*)p; p += (size_t)kH * kDFF / 2;
  ushort_t* WT2 = (ushort_t*)p; p += (size_t)kDFF * kH / 2;
  ushort_t* ffn_bf = (ushort_t*)p; p += (size_t)kM * kDFF / 2;

  float* qb = qkf;
  float* kb = qkf + (size_t)kM * kH;

  hipMemcpyAsync(x, content, (size_t)kM * kH * sizeof(float), hipMemcpyDeviceToDevice, stream);
  sincos_kernel<<<kB * kL * 32 / 256, 256, 0, stream>>>(leaf_idx, sinT, cosT);

  for (int i = 0; i < kNL; i++) {
    tconv_kernel<<<dim3(16, 16), 256, 0, stream>>>(Wq + (size_t)i * kH * kH, WTqkv, kH, kH);
    tconv_kernel<<<dim3(16, 16), 256, 0, stream>>>(Wk + (size_t)i * kH * kH, WTqkv + (size_t)kH * kH, kH, kH);
    tconv_kernel<<<dim3(16, 16), 256, 0, stream>>>(Wv + (size_t)i * kH * kH, WTqkv + (size_t)2 * kH * kH, kH, kH);
    tconv_kernel<<<dim3(16, 16), 256, 0, stream>>>(Wo + (size_t)i * kH * kH, WTo, kH, kH);
    tconv_kernel<<<dim3(64, 16), 256, 0, stream>>>(W1 + (size_t)i * kH * kDFF, WT1, kH, kDFF);
    tconv_kernel<<<dim3(16, 64), 256, 0, stream>>>(W2 + (size_t)i * kDFF * kH, WT2, kDFF, kH);

    ln_kernel<<<kM, 256, 0, stream>>>(x, ln1_g + i * kH, ln1_b + i * kH, h_bf);
    mm_kernel<0><<<dim3(24, 16), 256, 0, stream>>>(h_bf, WTqkv, bq + i * kH, bk + i * kH,
                                                   bv + i * kH, qkf, vT, kH, 3 * kH);
    gate_kernel<<<kM, 256, 0, stream>>>(h_bf, Wg + (size_t)i * kH * kNH, bg + i * kNH, leaf_idx, gateb);
    rotary_kernel<<<kB * kNH * kL * 32 / 256, 256, 0, stream>>>(qb, kb, sinT, cosT,
                                                                qbf, tqbf, kbf, tkbf);
    fattn_kernel<<<kB * kNH * 8, 256, 0, stream>>>(qbf, tqbf, kbf, tkbf, vT, tree_score,
                                                   gateb, leaf_idx, ctx_bf);
    mm_kernel<1><<<dim3(8, 16), 256, 0, stream>>>(ctx_bf, WTo, bo + i * kH, nullptr, nullptr,
                                                  x, nullptr, kH, kH);
    ln_kernel<<<kM, 256, 0, stream>>>(x, ln2_g + i * kH, ln2_b + i * kH, h_bf);
    mm_kernel<2><<<dim3(32, 16), 256, 0, stream>>>(h_bf, WT1, b1 + i * kDFF, nullptr, nullptr,
                                                   nullptr, ffn_bf, kH, kDFF);
    mm_kernel<1><<<dim3(8, 16), 256, 0, stream>>>(ffn_bf, WT2, b2 + i * kH, nullptr, nullptr,
                                                  x, nullptr, kDFF, kH);
  }
}